// Round 12
// baseline (27.907 us; speedup 1.0000x reference)
//
#include <hip/hip_runtime.h>

#define H 128
#define N 1024

// ---------------------------------------------------------------------------
// prep: grid N/4 = 256 blocks x 512 threads (8 waves -> 8 waves/CU).
//   phase 1: waves 0-3 L2-normalize rows 0-3 (shuffle reduce).
//   phase 2: quarter q = t>>7: q<2 -> L-half of W1, q>=2 -> R-half;
//            rows {0,1} (q even) or {2,3} (q odd); h = t&127.
//            PF=8 register-pipelined W1 column loads.
//   Outputs (all scaled by w2[h], so relu(x)*w2 = s*|u| works downstream):
//     Lp[i][h] = w2[h]*(L[i][h] + b1[h])
//     Rt[h][j] = w2[h]*R[j][h]          (transposed for adj)
//     c[j]     = 0.5 * sum_h Rt[h][j]   (softmax-invariant part of logits)
// ---------------------------------------------------------------------------
__global__ __launch_bounds__(512) void prep_kernel(
    const float* __restrict__ x, const float* __restrict__ W1,
    const float* __restrict__ b1, const float* __restrict__ W2,
    float* __restrict__ Lp, float* __restrict__ Rt, float* __restrict__ c)
{
    constexpr int PF = 8;
    __shared__ float e_s[4][H];
    __shared__ float cred[4][2];
    const int t = threadIdx.x;
    const int i0 = blockIdx.x * 4;

    if (t < 256) {                       // normalize: wave w owns row w
        const int row = t >> 6, lane = t & 63;
        const float2 v = *reinterpret_cast<const float2*>(&x[(i0 + row) * H + 2 * lane]);
        float s = v.x * v.x + v.y * v.y;
#pragma unroll
        for (int off = 32; off; off >>= 1) s += __shfl_xor(s, off);
        const float rn = 1.0f / fmaxf(sqrtf(s), 1e-12f);
        e_s[row][2 * lane]     = v.x * rn;
        e_s[row][2 * lane + 1] = v.y * rn;
    }
    __syncthreads();

    const int h = t & (H - 1);
    const int q = t >> 7;                // 0,1 -> L ; 2,3 -> R
    const int r0 = (q & 1) * 2;          // row pair {0,1} or {2,3}
    const float* Wb = W1 + (q >= 2 ? H * H : 0) + h;

    float acc0 = 0.f, acc1 = 0.f;
    float wbuf[PF];
#pragma unroll
    for (int p = 0; p < PF; ++p) wbuf[p] = Wb[p * H];

    for (int kb = 0; kb < H - PF; kb += PF) {
#pragma unroll
        for (int p = 0; p < PF; ++p) {
            const float w = wbuf[p];
            wbuf[p] = Wb[(kb + p + PF) * H];
            acc0 = fmaf(e_s[r0][kb + p],     w, acc0);
            acc1 = fmaf(e_s[r0 + 1][kb + p], w, acc1);
        }
    }
#pragma unroll
    for (int p = 0; p < PF; ++p) {
        const int k = H - PF + p;
        acc0 = fmaf(e_s[r0][k],     wbuf[p], acc0);
        acc1 = fmaf(e_s[r0 + 1][k], wbuf[p], acc1);
    }

    const float w2h = W2[h];
    if (q < 2) {
        const float bb = b1[h];
        Lp[(i0 + r0) * H + h]     = w2h * (acc0 + bb);
        Lp[(i0 + r0 + 1) * H + h] = w2h * (acc1 + bb);
    } else {
        const float v0 = w2h * acc0, v1 = w2h * acc1;
        Rt[h * N + (i0 + r0)]     = v0;
        Rt[h * N + (i0 + r0 + 1)] = v1;
        float s0 = v0, s1 = v1;          // c_j partial sums over h
#pragma unroll
        for (int off = 32; off; off >>= 1) {
            s0 += __shfl_xor(s0, off);
            s1 += __shfl_xor(s1, off);
        }
        const int wv = t >> 6;           // 4..7
        if ((t & 63) == 0) { cred[wv - 4][0] = s0; cred[wv - 4][1] = s1; }
    }
    __syncthreads();
    if (t < 4) {                         // c[i0+r]: combine the 2 waves per row
        const int r = t;
        c[i0 + r] = 0.5f * (cred[(r >> 1) * 2][r & 1] + cred[(r >> 1) * 2 + 1][r & 1]);
    }
}

// ---------------------------------------------------------------------------
// adj: grid N/4 = 256 blocks x 512 threads (8 waves -> 2 waves/SIMD).
//   thread t: rows i0..i0+3, cols j0 = 2t, 2t+1.
//   logit'[i][j] = c[j] + sum_h s_h * |Lp[i][h] + Rt[h][j]|,  s_h = ±0.5
//   Inner loop: 2 VALU/element (v_add + v_fma with abs modifier),
//   Lp via one b128 LDS broadcast per h, sgn via b32 LDS broadcast.
//   SINGLE DELTA vs the 25.5 us baseline: PF=8 -> 16 rotating float2
//   B-prefetch (issue-to-use lead ~540 wave-cyc > L2 latency). Main loop
//   7 x 16 steps (hb 0..96), prefetch reaches row 127 exactly; 16-step tail.
// ---------------------------------------------------------------------------
__global__ __launch_bounds__(512) void adj_kernel(
    const float* __restrict__ Lp, const float* __restrict__ Rt,
    const float* __restrict__ W2, const float* __restrict__ c,
    float* __restrict__ out)
{
    constexpr int II = 4, PF = 16;
    __shared__ float LsT[H][4];
    __shared__ float sgn[H];
    __shared__ float red_m[II][8];
    __shared__ float red_s[II][8];

    const int t = threadIdx.x;
    const int lane = t & 63, wave = t >> 6;
    const int i0 = blockIdx.x * II;
    const int j0 = t * 2;

    if (t < H) {
        sgn[t] = (W2[t] >= 0.f) ? 0.5f : -0.5f;
        float4 lv;
        lv.x = Lp[(i0 + 0) * H + t];
        lv.y = Lp[(i0 + 1) * H + t];
        lv.z = Lp[(i0 + 2) * H + t];
        lv.w = Lp[(i0 + 3) * H + t];
        *reinterpret_cast<float4*>(&LsT[t][0]) = lv;
    }
    const float2 cj = *reinterpret_cast<const float2*>(&c[j0]);
    __syncthreads();

    float accx[II], accy[II];
#pragma unroll
    for (int ii = 0; ii < II; ++ii) { accx[ii] = cj.x; accy[ii] = cj.y; }

    float2 rbuf[PF];
#pragma unroll
    for (int p = 0; p < PF; ++p)
        rbuf[p] = *reinterpret_cast<const float2*>(&Rt[p * N + j0]);

    for (int hb = 0; hb < H - PF; hb += PF) {   // hb = 0,16,...,96
#pragma unroll
        for (int p = 0; p < PF; ++p) {
            const int h = hb + p;
            const float2 r = rbuf[p];
            rbuf[p] = *reinterpret_cast<const float2*>(&Rt[(h + PF) * N + j0]);
            const float4 lv = *reinterpret_cast<const float4*>(&LsT[h][0]);
            const float s = sgn[h];
            const float* lp = &lv.x;
#pragma unroll
            for (int ii = 0; ii < II; ++ii) {
                accx[ii] = fmaf(s, fabsf(lp[ii] + r.x), accx[ii]);
                accy[ii] = fmaf(s, fabsf(lp[ii] + r.y), accy[ii]);
            }
        }
    }
#pragma unroll
    for (int p = 0; p < PF; ++p) {       // tail: h = 112..127, no prefetch
        const int h = H - PF + p;
        const float2 r = rbuf[p];
        const float4 lv = *reinterpret_cast<const float4*>(&LsT[h][0]);
        const float s = sgn[h];
        const float* lp = &lv.x;
#pragma unroll
        for (int ii = 0; ii < II; ++ii) {
            accx[ii] = fmaf(s, fabsf(lp[ii] + r.x), accx[ii]);
            accy[ii] = fmaf(s, fabsf(lp[ii] + r.y), accy[ii]);
        }
    }

    // ---- softmax over j (block = full row) ----
#pragma unroll
    for (int ii = 0; ii < II; ++ii) {
        float m = fmaxf(accx[ii], accy[ii]);
#pragma unroll
        for (int off = 32; off; off >>= 1) m = fmaxf(m, __shfl_xor(m, off));
        if (lane == 0) red_m[ii][wave] = m;
    }
    __syncthreads();

    float mm[II];
#pragma unroll
    for (int ii = 0; ii < II; ++ii) {
        float m = red_m[ii][0];
#pragma unroll
        for (int w = 1; w < 8; ++w) m = fmaxf(m, red_m[ii][w]);
        mm[ii] = m;
    }

#pragma unroll
    for (int ii = 0; ii < II; ++ii) {
        accx[ii] = expf(accx[ii] - mm[ii]);
        accy[ii] = expf(accy[ii] - mm[ii]);
        float s = accx[ii] + accy[ii];
#pragma unroll
        for (int off = 32; off; off >>= 1) s += __shfl_xor(s, off);
        if (lane == 0) red_s[ii][wave] = s;
    }
    __syncthreads();

#pragma unroll
    for (int ii = 0; ii < II; ++ii) {
        float s = red_s[ii][0];
#pragma unroll
        for (int w = 1; w < 8; ++w) s += red_s[ii][w];
        const float r = 1.0f / s;
        float2 o;
        o.x = accx[ii] * r;
        o.y = accy[ii] * r;
        *reinterpret_cast<float2*>(&out[(i0 + ii) * N + j0]) = o;
    }
}

extern "C" void kernel_launch(void* const* d_in, const int* in_sizes, int n_in,
                              void* d_out, int out_size, void* d_ws, size_t ws_size,
                              hipStream_t stream) {
    const float* x  = (const float*)d_in[0];   // (N,H)
    const float* W1 = (const float*)d_in[1];   // (2H,H)
    const float* b1 = (const float*)d_in[2];   // (H,)
    const float* W2 = (const float*)d_in[3];   // (H,1)
    // d_in[4] = b2 — cancels under softmax, not needed.
    float* out = (float*)d_out;

    float* Lp = (float*)d_ws;        // N*H
    float* Rt = Lp + N * H;          // H*N (transposed, w2-scaled)
    float* cc = Rt + H * N;          // N

    prep_kernel<<<N / 4, 512, 0, stream>>>(x, W1, b1, W2, Lp, Rt, cc);
    adj_kernel<<<N / 4, 512, 0, stream>>>(Lp, Rt, W2, cc, out);
}